// Round 1
// 860.172 us; speedup vs baseline: 1.0233x; 1.0233x over previous
//
#include <hip/hip_runtime.h>

// Problem constants (fixed by reference setup_inputs)
constexpr int T_DIM = 10, C_DIM = 3, H_DIM = 512, W_DIM = 512;
constexpr int PT = 2, PS = 7;
constexpr int ELEM_PER_Q = PT * C_DIM * PS * PS;  // 294
constexpr int HALF      = C_DIM * PS * PS;        // 147 (one dt-slice of a patch)
constexpr int TILE = 38;                           // exclusive output tile (h,w)
constexpr int NBH = 14, NBW = 14;                  // anchor bins: ceil(506/38)=14
constexpr int NTB = T_DIM - PT + 1;                // 9 anchor t values
constexpr int NBINS = NTB * NBH * NBW;             // 1764
constexpr int BINPAD = 2048;

// d_ws layout (ints): counts[2048] | offsets[2048] | cursors[2048] | list[Q]
// list entry packing: q in bits [0,18), dh=h-sh*TILE in [18,24), dw=w-sw*TILE in [24,30)
// (valid because Q = 262144 = 2^18 and dh,dw < TILE = 38 < 64)

__global__ __launch_bounds__(256) void ScatterNL_hist(
    const int* __restrict__ qinds, int Q, int* __restrict__ counts)
{
    __shared__ int hloc[NBINS];
    for (int i = threadIdx.x; i < NBINS; i += blockDim.x) hloc[i] = 0;
    __syncthreads();
    int stride = gridDim.x * blockDim.x;
    for (int q = blockIdx.x * blockDim.x + threadIdx.x; q < Q; q += stride) {
        int t = qinds[3*q], h = qinds[3*q+1], w = qinds[3*q+2];
        int b = (t * NBH + h / TILE) * NBW + w / TILE;
        atomicAdd(&hloc[b], 1);
    }
    __syncthreads();
    for (int i = threadIdx.x; i < NBINS; i += blockDim.x)
        if (hloc[i]) atomicAdd(&counts[i], hloc[i]);
}

// 256 threads, each owns 7 consecutive bins (256*7=1792 >= 1764).
__global__ __launch_bounds__(256) void ScatterNL_scan(
    const int* __restrict__ counts, int* __restrict__ offsets,
    int* __restrict__ cursors)
{
    __shared__ int buf[2][256];
    int tid = threadIdx.x;
    int base = tid * 7;
    int loc[7];
    int s = 0;
    #pragma unroll
    for (int i = 0; i < 7; ++i) {
        int b = base + i;
        int v = (b < NBINS) ? counts[b] : 0;
        loc[i] = s;            // exclusive within this thread's chunk
        s += v;
    }
    buf[0][tid] = s;
    __syncthreads();
    int src = 0;
    for (int d = 1; d < 256; d <<= 1) {
        int x = buf[src][tid] + ((tid >= d) ? buf[src][tid - d] : 0);
        buf[src ^ 1][tid] = x;
        __syncthreads();
        src ^= 1;
    }
    int excl = (tid == 0) ? 0 : buf[src][tid - 1];
    #pragma unroll
    for (int i = 0; i < 7; ++i) {
        int b = base + i;
        if (b < NBINS) {
            offsets[b] = excl + loc[i];
            cursors[b] = excl + loc[i];
        }
    }
    if (tid == 255) offsets[NBINS] = buf[src][255];
}

__global__ __launch_bounds__(256) void ScatterNL_fill(
    const int* __restrict__ qinds, int Q, int* __restrict__ cursors,
    int* __restrict__ list)
{
    int stride = gridDim.x * blockDim.x;
    for (int q = blockIdx.x * blockDim.x + threadIdx.x; q < Q; q += stride) {
        int t = qinds[3*q], h = qinds[3*q+1], w = qinds[3*q+2];
        int sh = h / TILE, sw = w / TILE;
        int b = (t * NBH + sh) * NBW + sw;
        int pos = atomicAdd(&cursors[b], 1);
        // pack q + bin-relative coords so accum never touches qinds
        list[pos] = q | ((h - sh * TILE) << 18) | ((w - sw * TILE) << 24);
    }
}

__global__ __launch_bounds__(256) void ScatterNL_accum(
    const float* __restrict__ vid, const float* __restrict__ patches,
    const int* __restrict__ offsets,
    const int* __restrict__ list, float* __restrict__ out)
{
    __shared__ float acc[C_DIM * TILE * TILE];   // 17,328 B

    int bid = blockIdx.x;
    int ts  = bid / (NBH * NBW);                 // output t-slice 0..9
    int r   = bid % (NBH * NBW);
    int bh  = r / NBW, bw = r % NBW;
    int h0  = bh * TILE, w0 = bw * TILE;
    int THe = min(TILE, H_DIM - h0);             // 38 (18 on last row)
    int TWe = min(TILE, W_DIM - w0);

    for (int i = threadIdx.x; i < C_DIM * TILE * TILE; i += blockDim.x)
        acc[i] = 0.f;
    __syncthreads();

    const int lane = threadIdx.x & 63;
    const int wv   = threadIdx.x >> 6;           // 0..3
    const int NW   = blockDim.x >> 6;            // 4 waves

    // Per-lane (c,i,j) for k = lane, lane+64, lane+128. Segments 0,1 fully
    // valid (k<=127<147); segment 2 valid for lane<19.
    int cc[3], ii[3], jj[3];
    #pragma unroll
    for (int s = 0; s < 3; ++s) {
        int k = lane + 64 * s;
        int kk = (k < HALF) ? k : 0;
        cc[s] = kk / 49;
        int rr = kk % 49;
        ii[s] = rr / 7;
        jj[s] = rr % 7;
    }
    const bool v2ok = (lane < HALF - 128);       // lane < 19

    auto accum1 = [&](int hws, float v0, float v1, float v2) {
        int qhs = hws >> 16, qws = hws & 0xffff;
        #pragma unroll
        for (int s = 0; s < 3; ++s) {
            float v = (s == 0) ? v0 : (s == 1) ? v1 : v2;
            bool lv = (s < 2) || v2ok;
            int hh = qhs + ii[s] - h0;
            int ww = qws + jj[s] - w0;
            if (lv && hh >= 0 && hh < THe && ww >= 0 && ww < TWe)
                atomicAdd(&acc[(cc[s] * TILE + hh) * TILE + ww], v);
        }
    };

    for (int tb = ts - 1; tb <= ts; ++tb) {
        if (tb < 0 || tb > T_DIM - PT) continue;
        int dt = ts - tb;                        // which patch half lands in slice ts
        for (int sh = max(bh - 1, 0); sh <= bh; ++sh) {
            for (int sw = max(bw - 1, 0); sw <= bw; ++sw) {
                int bin   = (tb * NBH + sh) * NBW + sw;
                int start = offsets[bin], end = offsets[bin + 1];
                int nb    = (end - start + 63) >> 6;
                for (int bi = wv; bi < nb; bi += NW) {
                    int e = start + (bi << 6) + lane;
                    bool inb = (e < end);
                    int ent = inb ? list[e] : 0;         // single coalesced load
                    int q   = ent & 0x3FFFF;
                    int qh  = sh * TILE + ((ent >> 18) & 63);
                    int qw  = sw * TILE + ((ent >> 24) & 63);
                    bool ok = inb && (qh + PS > h0) && (qh < h0 + THe)
                                  && (qw + PS > w0) && (qw < w0 + TWe);
                    int hw = (qh << 16) | qw;
                    unsigned long long m = __ballot(ok);
                    // Depth-4 batching: pop up to 4 patches, issue all 12
                    // global loads before any LDS atomic -> 4x MLP per wave.
                    while (m) {
                        int s0 = __ffsll((long long)m) - 1; m &= m - 1;
                        int s1 = s0, s2 = s0, s3 = s0;
                        const bool h1 = (m != 0);
                        if (h1) { s1 = __ffsll((long long)m) - 1; m &= m - 1; }
                        const bool h2 = (m != 0);
                        if (h2) { s2 = __ffsll((long long)m) - 1; m &= m - 1; }
                        const bool h3 = (m != 0);
                        if (h3) { s3 = __ffsll((long long)m) - 1; m &= m - 1; }

                        int q0 = __shfl(q, s0), hw0 = __shfl(hw, s0);
                        int q1 = __shfl(q, s1), hw1 = __shfl(hw, s1);
                        int q2 = __shfl(q, s2), hw2 = __shfl(hw, s2);
                        int q3 = __shfl(q, s3), hw3 = __shfl(hw, s3);

                        const float* B0 = patches + (size_t)q0 * ELEM_PER_Q + dt * HALF;
                        const float* B1 = patches + (size_t)q1 * ELEM_PER_Q + dt * HALF;
                        const float* B2 = patches + (size_t)q2 * ELEM_PER_Q + dt * HALF;
                        const float* B3 = patches + (size_t)q3 * ELEM_PER_Q + dt * HALF;

                        float a00 = B0[lane], a01 = B0[lane + 64], a02 = v2ok ? B0[lane + 128] : 0.f;
                        float a10 = B1[lane], a11 = B1[lane + 64], a12 = v2ok ? B1[lane + 128] : 0.f;
                        float a20 = B2[lane], a21 = B2[lane + 64], a22 = v2ok ? B2[lane + 128] : 0.f;
                        float a30 = B3[lane], a31 = B3[lane + 64], a32 = v2ok ? B3[lane + 128] : 0.f;

                        // Keep the load cluster above the atomics so the
                        // backend emits staged vmcnt drains (loads 1..3 stay
                        // in flight during patch-0 atomics).
                        __builtin_amdgcn_sched_barrier(0);

                        accum1(hw0, a00, a01, a02);
                        if (h1) accum1(hw1, a10, a11, a12);
                        if (h2) accum1(hw2, a20, a21, a22);
                        if (h3) accum1(hw3, a30, a31, a32);
                    }
                }
            }
        }
    }
    __syncthreads();

    // Exclusive write-out: out = vid2fill + acc. Each output element written once.
    #pragma unroll
    for (int c = 0; c < C_DIM; ++c) {
        for (int y = wv; y < THe; y += NW) {
            if (lane < TWe) {
                size_t o = (((size_t)ts * C_DIM + c) * H_DIM + (h0 + y)) * W_DIM + w0 + lane;
                out[o] = vid[o] + acc[(c * TILE + y) * TILE + lane];
            }
        }
    }
}

extern "C" void kernel_launch(void* const* d_in, const int* in_sizes, int n_in,
                              void* d_out, int out_size, void* d_ws, size_t ws_size,
                              hipStream_t stream) {
    const float* vid     = (const float*)d_in[0];
    const float* patches = (const float*)d_in[1];
    const int*   qinds   = (const int*)d_in[2];
    float* out = (float*)d_out;
    int Q = in_sizes[2] / 3;

    int* ws      = (int*)d_ws;
    int* counts  = ws;
    int* offsets = ws + BINPAD;
    int* cursors = ws + 2 * BINPAD;
    int* list    = ws + 3 * BINPAD;

    hipMemsetAsync(counts, 0, BINPAD * sizeof(int), stream);  // ws is poisoned each call
    ScatterNL_hist<<<256, 256, 0, stream>>>(qinds, Q, counts);
    ScatterNL_scan<<<1, 256, 0, stream>>>(counts, offsets, cursors);
    ScatterNL_fill<<<256, 256, 0, stream>>>(qinds, Q, cursors, list);
    ScatterNL_accum<<<T_DIM * NBH * NBW, 256, 0, stream>>>(
        vid, patches, offsets, list, out);
}

// Round 2
// 847.208 us; speedup vs baseline: 1.0389x; 1.0153x over previous
//
#include <hip/hip_runtime.h>

// Problem constants (fixed by reference setup_inputs)
constexpr int T_DIM = 10, C_DIM = 3, H_DIM = 512, W_DIM = 512;
constexpr int PT = 2, PS = 7;
constexpr int ELEM_PER_Q = PT * C_DIM * PS * PS;  // 294
constexpr int HALF      = C_DIM * PS * PS;        // 147 (one dt-slice of a patch)
constexpr int TILE = 38;                           // anchor bin & output tile (h,w)
constexpr int NBH = 14, NBW = 14;                  // ceil(506/38)=14
constexpr int NTB = T_DIM - PT + 1;                // 9 anchor t values
constexpr int NBINS = NTB * NBH * NBW;             // 1764
constexpr int BINPAD = 2048;
constexpr int HTILE = TILE + PS - 1;               // 44: tile + down-right halo
constexpr int ACC_SLICE = C_DIM * HTILE * HTILE;   // 5808 floats per t-slice
constexpr int NPAIR = T_DIM / 2;                   // 5 t-pairs

// d_ws layout (ints): counts[2048] | offsets[2048] | cursors[2048] | list[Q]
// list entry packing: q[0,18) | dh[18,24) | dw[24,30)  (dh,dw < TILE=38 < 64)

__global__ __launch_bounds__(256) void ScatterNL_hist(
    const int* __restrict__ qinds, int Q, int* __restrict__ counts)
{
    __shared__ int hloc[NBINS];
    for (int i = threadIdx.x; i < NBINS; i += blockDim.x) hloc[i] = 0;
    __syncthreads();
    int stride = gridDim.x * blockDim.x;
    for (int q = blockIdx.x * blockDim.x + threadIdx.x; q < Q; q += stride) {
        int t = qinds[3*q], h = qinds[3*q+1], w = qinds[3*q+2];
        int b = (t * NBH + h / TILE) * NBW + w / TILE;
        atomicAdd(&hloc[b], 1);
    }
    __syncthreads();
    for (int i = threadIdx.x; i < NBINS; i += blockDim.x)
        if (hloc[i]) atomicAdd(&counts[i], hloc[i]);
}

// 256 threads, each owns 7 consecutive bins (256*7=1792 >= 1764).
__global__ __launch_bounds__(256) void ScatterNL_scan(
    const int* __restrict__ counts, int* __restrict__ offsets,
    int* __restrict__ cursors)
{
    __shared__ int buf[2][256];
    int tid = threadIdx.x;
    int base = tid * 7;
    int loc[7];
    int s = 0;
    #pragma unroll
    for (int i = 0; i < 7; ++i) {
        int b = base + i;
        int v = (b < NBINS) ? counts[b] : 0;
        loc[i] = s;
        s += v;
    }
    buf[0][tid] = s;
    __syncthreads();
    int src = 0;
    for (int d = 1; d < 256; d <<= 1) {
        int x = buf[src][tid] + ((tid >= d) ? buf[src][tid - d] : 0);
        buf[src ^ 1][tid] = x;
        __syncthreads();
        src ^= 1;
    }
    int excl = (tid == 0) ? 0 : buf[src][tid - 1];
    #pragma unroll
    for (int i = 0; i < 7; ++i) {
        int b = base + i;
        if (b < NBINS) {
            offsets[b] = excl + loc[i];
            cursors[b] = excl + loc[i];
        }
    }
    if (tid == 255) offsets[NBINS] = buf[src][255];
}

__global__ __launch_bounds__(256) void ScatterNL_fill(
    const int* __restrict__ qinds, int Q, int* __restrict__ cursors,
    int* __restrict__ list)
{
    int stride = gridDim.x * blockDim.x;
    for (int q = blockIdx.x * blockDim.x + threadIdx.x; q < Q; q += stride) {
        int t = qinds[3*q], h = qinds[3*q+1], w = qinds[3*q+2];
        int sh = h / TILE, sw = w / TILE;
        int b = (t * NBH + sh) * NBW + sw;
        int pos = atomicAdd(&cursors[b], 1);
        list[pos] = q | ((h - sh * TILE) << 18) | ((w - sw * TILE) << 24);
    }
}

// out = vid (accum then atomically adds patch contributions)
__global__ __launch_bounds__(256) void ScatterNL_copy(
    const float* __restrict__ vid, float* __restrict__ out, int n4)
{
    int stride = gridDim.x * blockDim.x;
    const float4* src = (const float4*)vid;
    float4* dst = (float4*)out;
    for (int i = blockIdx.x * blockDim.x + threadIdx.x; i < n4; i += stride)
        dst[i] = src[i];
}

// Block = (t-pair k, bh, bw). Owns output slices 2k, 2k+1 over a 44x44
// halo'd tile. Visits ONLY bins (tb, bh, bw) for tb in {2k-1, 2k, 2k+1}:
//   tb=2k   -> full 1176B patch read (both halves land in owned slices)
//   tb=2k+1 -> first half (dt=0) -> local slice 1
//   tb=2k-1 -> second half (dt=1) -> local slice 0
// Every entry contributes (no filtering); halo guarantees in-range scatter.
__global__ __launch_bounds__(512, 6) void ScatterNL_accum(
    const float* __restrict__ patches, const int* __restrict__ offsets,
    const int* __restrict__ list, float* __restrict__ out)
{
    __shared__ float acc[2 * ACC_SLICE];         // 46,464 B -> 3 blocks/CU

    int bid = blockIdx.x;
    int k   = bid / (NBH * NBW);                 // t-pair 0..4
    int r   = bid % (NBH * NBW);
    int bh  = r / NBW, bw = r % NBW;
    int h0  = bh * TILE, w0 = bw * TILE;

    for (int i = threadIdx.x; i < 2 * ACC_SLICE; i += blockDim.x)
        acc[i] = 0.f;
    __syncthreads();

    const int lane = threadIdx.x & 63;
    const int wv   = threadIdx.x >> 6;           // 0..7
    // Per-lane scatter offsets. Half (147 elems): segs s=0..2, k=lane+64s.
    int off3[3];
    #pragma unroll
    for (int s = 0; s < 3; ++s) {
        int kx = lane + 64 * s;
        int kk = (kx < HALF) ? kx : 0;
        int c = kk / 49, rr = kk % 49;
        off3[s] = (c * HTILE + rr / 7) * HTILE + rr % 7;
    }
    const bool v2ok = (lane < HALF - 128);       // lane < 19
    // Full (294 elems): segs s=0..4; seg 4 valid lane<38. sl = which slice.
    int offf[5], slf[5];
    #pragma unroll
    for (int s = 0; s < 5; ++s) {
        int kx = lane + 64 * s;
        int kk = (kx < ELEM_PER_Q) ? kx : 0;
        slf[s] = kk / HALF;
        int rem = kk % HALF;
        int c = rem / 49, rr = rem % 49;
        offf[s] = slf[s] * ACC_SLICE + (c * HTILE + rr / 7) * HTILE + rr % 7;
    }
    const bool v4ok = (lane < ELEM_PER_Q - 256); // lane < 38

    // ---- half-patch bins (batch 4 per wave-iteration) ----
    auto procHalf = [&](int bin, int dtOff, int ss) {
        int start = offsets[bin], n = offsets[bin + 1] - start;
        int sbase = ss * ACC_SLICE;
        for (int base = wv * 4; base < n; base += 32) {
            int i0 = start + base;
            int nb = n - base;                   // >=1
            int e0 = list[i0];
            int e1 = (nb > 1) ? list[i0 + 1] : e0;
            int e2 = (nb > 2) ? list[i0 + 2] : e0;
            int e3 = (nb > 3) ? list[i0 + 3] : e0;
            const float* B0 = patches + (size_t)(e0 & 0x3FFFF) * ELEM_PER_Q + dtOff;
            const float* B1 = patches + (size_t)(e1 & 0x3FFFF) * ELEM_PER_Q + dtOff;
            const float* B2 = patches + (size_t)(e2 & 0x3FFFF) * ELEM_PER_Q + dtOff;
            const float* B3 = patches + (size_t)(e3 & 0x3FFFF) * ELEM_PER_Q + dtOff;
            float a00 = B0[lane], a01 = B0[lane+64], a02 = v2ok ? B0[lane+128] : 0.f;
            float a10 = B1[lane], a11 = B1[lane+64], a12 = v2ok ? B1[lane+128] : 0.f;
            float a20 = B2[lane], a21 = B2[lane+64], a22 = v2ok ? B2[lane+128] : 0.f;
            float a30 = B3[lane], a31 = B3[lane+64], a32 = v2ok ? B3[lane+128] : 0.f;
            __builtin_amdgcn_sched_barrier(0);   // keep load cluster above atomics
            int d0 = sbase + ((e0 >> 18) & 63) * HTILE + ((e0 >> 24) & 63);
            int d1 = sbase + ((e1 >> 18) & 63) * HTILE + ((e1 >> 24) & 63);
            int d2 = sbase + ((e2 >> 18) & 63) * HTILE + ((e2 >> 24) & 63);
            int d3 = sbase + ((e3 >> 18) & 63) * HTILE + ((e3 >> 24) & 63);
            atomicAdd(&acc[d0 + off3[0]], a00);
            atomicAdd(&acc[d0 + off3[1]], a01);
            if (v2ok) atomicAdd(&acc[d0 + off3[2]], a02);
            if (nb > 1) {
                atomicAdd(&acc[d1 + off3[0]], a10);
                atomicAdd(&acc[d1 + off3[1]], a11);
                if (v2ok) atomicAdd(&acc[d1 + off3[2]], a12);
            }
            if (nb > 2) {
                atomicAdd(&acc[d2 + off3[0]], a20);
                atomicAdd(&acc[d2 + off3[1]], a21);
                if (v2ok) atomicAdd(&acc[d2 + off3[2]], a22);
            }
            if (nb > 3) {
                atomicAdd(&acc[d3 + off3[0]], a30);
                atomicAdd(&acc[d3 + off3[1]], a31);
                if (v2ok) atomicAdd(&acc[d3 + off3[2]], a32);
            }
        }
    };

    // ---- full-patch bin (batch 2 per wave-iteration) ----
    {
        int bin = (2 * k * NBH + bh) * NBW + bw;
        int start = offsets[bin], n = offsets[bin + 1] - start;
        for (int base = wv * 2; base < n; base += 16) {
            int i0 = start + base;
            int nb = n - base;
            int e0 = list[i0];
            int e1 = (nb > 1) ? list[i0 + 1] : e0;
            const float* B0 = patches + (size_t)(e0 & 0x3FFFF) * ELEM_PER_Q;
            const float* B1 = patches + (size_t)(e1 & 0x3FFFF) * ELEM_PER_Q;
            float a0[5], a1[5];
            #pragma unroll
            for (int s = 0; s < 5; ++s) {
                bool v = (s < 4) || v4ok;
                a0[s] = v ? B0[lane + 64*s] : 0.f;
                a1[s] = v ? B1[lane + 64*s] : 0.f;
            }
            __builtin_amdgcn_sched_barrier(0);
            int d0 = ((e0 >> 18) & 63) * HTILE + ((e0 >> 24) & 63);
            int d1 = ((e1 >> 18) & 63) * HTILE + ((e1 >> 24) & 63);
            #pragma unroll
            for (int s = 0; s < 5; ++s)
                if ((s < 4) || v4ok) atomicAdd(&acc[d0 + offf[s]], a0[s]);
            if (nb > 1) {
                #pragma unroll
                for (int s = 0; s < 5; ++s)
                    if ((s < 4) || v4ok) atomicAdd(&acc[d1 + offf[s]], a1[s]);
            }
        }
    }
    // tb = 2k+1: first half (dt=0) -> local slice 1
    if (2 * k + 1 <= T_DIM - PT)
        procHalf(((2 * k + 1) * NBH + bh) * NBW + bw, 0, 1);
    // tb = 2k-1: second half (dt=1) -> local slice 0
    if (2 * k - 1 >= 0)
        procHalf(((2 * k - 1) * NBH + bh) * NBW + bw, HALF, 0);

    __syncthreads();

    // Atomic write-out of the halo'd tile (out pre-filled with vid).
    int He = min(HTILE, H_DIM - h0);
    int We = min(HTILE, W_DIM - w0);
    for (int ls = 0; ls < 2; ++ls) {
        int ts = 2 * k + ls;
        #pragma unroll
        for (int c = 0; c < C_DIM; ++c) {
            for (int y = wv; y < He; y += 8) {
                if (lane < We) {
                    float v = acc[(ls * C_DIM + c) * HTILE * HTILE + y * HTILE + lane];
                    size_t o = (((size_t)ts * C_DIM + c) * H_DIM + (h0 + y)) * W_DIM + w0 + lane;
                    atomicAdd(&out[o], v);
                }
            }
        }
    }
}

extern "C" void kernel_launch(void* const* d_in, const int* in_sizes, int n_in,
                              void* d_out, int out_size, void* d_ws, size_t ws_size,
                              hipStream_t stream) {
    const float* vid     = (const float*)d_in[0];
    const float* patches = (const float*)d_in[1];
    const int*   qinds   = (const int*)d_in[2];
    float* out = (float*)d_out;
    int Q = in_sizes[2] / 3;

    int* ws      = (int*)d_ws;
    int* counts  = ws;
    int* offsets = ws + BINPAD;
    int* cursors = ws + 2 * BINPAD;
    int* list    = ws + 3 * BINPAD;

    hipMemsetAsync(counts, 0, BINPAD * sizeof(int), stream);  // ws is poisoned each call
    ScatterNL_copy<<<1024, 256, 0, stream>>>(vid, out,
        T_DIM * C_DIM * H_DIM * W_DIM / 4);
    ScatterNL_hist<<<256, 256, 0, stream>>>(qinds, Q, counts);
    ScatterNL_scan<<<1, 256, 0, stream>>>(counts, offsets, cursors);
    ScatterNL_fill<<<256, 256, 0, stream>>>(qinds, Q, cursors, list);
    ScatterNL_accum<<<NPAIR * NBH * NBW, 512, 0, stream>>>(
        patches, offsets, list, out);
}